// Round 1
// baseline (27.207 us; speedup 1.0000x reference)
//
#include <hip/hip_runtime.h>

#define NCLS 20

__global__ __launch_bounds__(256) void yolo_kernel(const float* __restrict__ x,
                                                   float* __restrict__ boxes,
                                                   float* __restrict__ scores,
                                                   float* __restrict__ idxs,
                                                   int B) {
    int t = blockIdx.x * blockDim.x + threadIdx.x;
    int total = B * 49;
    if (t >= total) return;
    int batch = t / 49;
    int cell = t - batch * 49;
    int row = cell / 7;
    int col = cell - row * 7;

    const float* xb = x + (size_t)batch * 30 * 49 + cell;

    // class scores (channels 10..29)
    float cls[NCLS];
    #pragma unroll
    for (int i = 0; i < NCLS; ++i) cls[i] = xb[(10 + i) * 49];

    float gx = (float)col;  // gi[0] = column index
    float gy = (float)row;  // gi[1] = row index

    #pragma unroll
    for (int b = 0; b < 2; ++b) {
        float d0   = xb[(b * 5 + 0) * 49];
        float d1   = xb[(b * 5 + 1) * 49];
        float d2   = xb[(b * 5 + 2) * 49];
        float d3   = xb[(b * 5 + 3) * 49];
        float conf = xb[(b * 5 + 4) * 49];

        // weighted = cls * conf; max + first-occurrence argmax (strict >)
        float best = cls[0] * conf;
        int bi = 0;
        #pragma unroll
        for (int i = 1; i < NCLS; ++i) {
            float w = cls[i] * conf;
            if (w > best) { best = w; bi = i; }
        }

        float cxv = (d0 + gx) / 7.0f;
        float cyv = (d1 + gy) / 7.0f;
        float hx = d2 * 0.5f;
        float hy = d3 * 0.5f;

        int orow = b * 49 + cell;
        size_t obase = (size_t)batch * 98 + orow;
        float4 bx = make_float4(cxv - hx, cyv - hy, cxv + hx, cyv + hy);
        *reinterpret_cast<float4*>(boxes + obase * 4) = bx;
        scores[obase] = best;
        idxs[obase]   = (float)bi;
    }
}

extern "C" void kernel_launch(void* const* d_in, const int* in_sizes, int n_in,
                              void* d_out, int out_size, void* d_ws, size_t ws_size,
                              hipStream_t stream) {
    const float* x = (const float*)d_in[0];
    int B = in_sizes[0] / (30 * 49);   // 16384

    float* out    = (float*)d_out;
    float* boxes  = out;                                 // B*98*4
    float* scores = out + (size_t)B * 98 * 4;            // B*98
    float* idxs   = scores + (size_t)B * 98;             // B*98

    int total = B * 49;
    int block = 256;
    int grid = (total + block - 1) / block;
    hipLaunchKernelGGL(yolo_kernel, dim3(grid), dim3(block), 0, stream,
                       x, boxes, scores, idxs, B);
}